// Round 1
// baseline (123.829 us; speedup 1.0000x reference)
//
#include <hip/hip_runtime.h>
#include <hip/hip_bf16.h>

#define BS 64
#define LS 512
#define CL 32
#define NW 50000
#define WD 300
#define NC 100
#define CD 100
#define NP 50
#define PD 100
#define NF 100
#define KK 3
#define OPAD 104                 // filter dim padded so per-k row is 8B-aligned
#define PROW (KK*OPAD)           // 312 bf16 per char = 624 B
#define PBYTES (NC*PROW*2)       // 62400 B
#define OUTD 501
#define TPB 8                    // tokens per block in main kernel

// ---------- Kernel 1: P[c][k][o] = sum_i conv_w[o,i,k] * char_table[c,i] ----------
__global__ void precompute_P(const float* __restrict__ conv_w,
                             const float* __restrict__ char_table,
                             __hip_bfloat16* __restrict__ P) {
    const int c = blockIdx.x;      // 0..99
    const int k = blockIdx.y;      // 0..2
    const int o = threadIdx.x;     // 0..127
    __shared__ float row[CD];
    if (o < CD) row[o] = char_table[c * CD + o];
    __syncthreads();
    float acc = 0.f;
    if (o < NF) {
        const float* w = conv_w + o * (CD * KK) + k;
        #pragma unroll 4
        for (int i = 0; i < CD; ++i) acc += w[i * KK] * row[i];
    }
    if (o < OPAD) P[(c * KK + k) * OPAD + o] = __float2bfloat16(acc);
}

// ---------- Kernel 2: nearest-privacy-token distance via Hillis-Steele scans ----------
__global__ void dist_kernel(const int* __restrict__ pos, float* __restrict__ dis) {
    const int b = blockIdx.x;
    const int j = threadIdx.x;     // 0..511
    __shared__ int sl[LS], sn[LS];
    const int p = pos[b * LS + j];
    const bool pm = (p == 3) | (p == 7) | (p == 11);
    sl[j] = pm ? j : -1000;
    sn[j] = pm ? j : 1000;
    __syncthreads();
    for (int off = 1; off < LS; off <<= 1) {
        const int vl = (j >= off)      ? sl[j - off] : -1000;
        const int vn = (j + off < LS)  ? sn[j + off] : 1000;
        __syncthreads();
        if (vl > sl[j]) sl[j] = vl;
        if (vn < sn[j]) sn[j] = vn;
        __syncthreads();
    }
    dis[b * LS + j] = (float)min(j - sl[j], sn[j] - j);
}

__device__ __forceinline__ void unpack4(uint2 r, float* p) {
    p[0] = __uint_as_float(r.x << 16);
    p[1] = __uint_as_float(r.x & 0xFFFF0000u);
    p[2] = __uint_as_float(r.y << 16);
    p[3] = __uint_as_float(r.y & 0xFFFF0000u);
}

// ---------- Kernel 3: main fused kernel ----------
__global__ __launch_bounds__(256) void main_kernel(
        const int* __restrict__ input_word,
        const int* __restrict__ input_char,
        const int* __restrict__ input_pos,
        const float* __restrict__ word_table,
        const float* __restrict__ pos_table,
        const float* __restrict__ conv_b,
        const __hip_bfloat16* __restrict__ Pg,
        const float* __restrict__ dis,
        float* __restrict__ out) {
    __shared__ __hip_bfloat16 Pl[NC * PROW];   // 62400 B
    __shared__ int s_addr[TPB * CL];           // 1024 B: precomputed LDS byte addr per char

    const int tid  = threadIdx.x;
    const int tok0 = blockIdx.x * TPB;

    // stage P into LDS as uint4 (3900 x 16B)
    {
        const uint4* src = (const uint4*)Pg;
        uint4* dst = (uint4*)Pl;
        for (int i = tid; i < PBYTES / 16; i += 256) dst[i] = src[i];
    }
    // stage char LDS base addresses (TPB*CL == 256, one per thread)
    s_addr[tid] = input_char[tok0 * CL + tid] * (PROW * 2);

    // ---- copies with no LDS dependency: overlap with P staging latency ----
    // word: out[:, 1:301]
    for (int e = tid; e < TPB * WD; e += 256) {
        const int t = e / WD, j = e - t * WD;
        const int w = input_word[tok0 + t];
        out[(size_t)(tok0 + t) * OUTD + 1 + j] = word_table[(size_t)w * WD + j];
    }
    // pos: out[:, 401:501]
    for (int e = tid; e < TPB * PD; e += 256) {
        const int t = e / PD, j = e - t * PD;
        const int p = input_pos[tok0 + t];
        out[(size_t)(tok0 + t) * OUTD + 401 + j] = pos_table[p * PD + j];
    }
    // dis: out[:, 0]
    if (tid < TPB) out[(size_t)(tok0 + tid) * OUTD] = dis[tok0 + tid];

    __syncthreads();

    // ---- char CNN: 25 threads per token, each owns 4 filters (one b64 quad) ----
    if (tid < TPB * 25) {
        const int tl = tid / 25;
        const int q  = tid - tl * 25;
        const char* Pb = (const char*)Pl;
        const int* ap = &s_addr[tl * CL];
        float a0[4] = {0.f, 0.f, 0.f, 0.f};
        float a1[4] = {0.f, 0.f, 0.f, 0.f};
        float m[4]  = {-1e30f, -1e30f, -1e30f, -1e30f};
        #pragma unroll 4
        for (int t = 0; t < CL; ++t) {
            const int ca = ap[t];                      // broadcast within token group
            uint2 r0 = *(const uint2*)(Pb + ca + 0 * (OPAD * 2) + q * 8);
            uint2 r1 = *(const uint2*)(Pb + ca + 1 * (OPAD * 2) + q * 8);
            uint2 r2 = *(const uint2*)(Pb + ca + 2 * (OPAD * 2) + q * 8);
            float p0[4], p1[4], p2[4];
            unpack4(r0, p0); unpack4(r1, p1); unpack4(r2, p2);
            #pragma unroll
            for (int i = 0; i < 4; ++i) {
                const float y = a0[i] + p2[i];         // y[t] complete
                m[i]  = fmaxf(m[i], y);
                a0[i] = a1[i] + p1[i];
                a1[i] = p0[i];
            }
        }
        const float4 b4 = *(const float4*)(conv_b + 4 * q);
        const float bb[4] = {b4.x, b4.y, b4.z, b4.w};
        float* outc = out + (size_t)(tok0 + tl) * OUTD + 301 + 4 * q;
        #pragma unroll
        for (int i = 0; i < 4; ++i) {
            // y[32] = a0, y[33] = a1 (tail of the sliding window)
            const float mm = fmaxf(m[i], fmaxf(a0[i], a1[i]));
            outc[i] = tanhf(mm + bb[i]);
        }
    }
}

extern "C" void kernel_launch(void* const* d_in, const int* in_sizes, int n_in,
                              void* d_out, int out_size, void* d_ws, size_t ws_size,
                              hipStream_t stream) {
    const int*   input_word = (const int*)d_in[0];
    const int*   input_char = (const int*)d_in[1];
    const int*   input_pos  = (const int*)d_in[2];
    const float* word_table = (const float*)d_in[3];
    const float* char_table = (const float*)d_in[4];
    const float* pos_table  = (const float*)d_in[5];
    const float* conv_w     = (const float*)d_in[6];
    const float* conv_b     = (const float*)d_in[7];
    float* out = (float*)d_out;

    __hip_bfloat16* P = (__hip_bfloat16*)d_ws;                 // 62400 B
    float* dis = (float*)((char*)d_ws + 65536);                // 131072 B

    precompute_P<<<dim3(NC, KK), 128, 0, stream>>>(conv_w, char_table, P);
    dist_kernel<<<BS, LS, 0, stream>>>(input_pos, dis);
    main_kernel<<<(BS * LS) / TPB, 256, 0, stream>>>(
        input_word, input_char, input_pos, word_table, pos_table, conv_b, P, dis, out);
}

// Round 2
// 57.902 us; speedup vs baseline: 2.1386x; 2.1386x over previous
//
#include <hip/hip_runtime.h>
#include <hip/hip_bf16.h>

#define BS 64
#define LS 512
#define CL 32
#define NW 50000
#define WD 300
#define NC 100
#define CD 100
#define NP 50
#define PD 100
#define NF 100
#define KK 3
#define OPAD 104                 // filter dim padded so per-k row is 8B-aligned
#define PROW (KK*OPAD)           // 312 bf16 per char = 624 B
#define PBYTES (NC*PROW*2)       // 62400 B
#define OUTD 501
#define TPB 32                   // tokens per block in main kernel
#define NTHR 1024

// ---------- Kernel 1: P[c][k][o] = sum_i conv_w[o,i,k] * char_table[c,i] ----------
__global__ void precompute_P(const float* __restrict__ conv_w,
                             const float* __restrict__ char_table,
                             __hip_bfloat16* __restrict__ P) {
    const int c = blockIdx.x;      // 0..99
    const int k = blockIdx.y;      // 0..2
    const int o = threadIdx.x;     // 0..127
    __shared__ float row[CD];
    if (o < CD) row[o] = char_table[c * CD + o];
    __syncthreads();
    float acc = 0.f;
    if (o < NF) {
        const float* w = conv_w + o * (CD * KK) + k;
        #pragma unroll 4
        for (int i = 0; i < CD; ++i) acc += w[i * KK] * row[i];
    }
    if (o < OPAD) P[(c * KK + k) * OPAD + o] = __float2bfloat16(acc);
}

// ---------- Kernel 2: privacy-distance scans; writes out column 0 directly ----------
__global__ void dist_kernel(const int* __restrict__ pos, float* __restrict__ out) {
    const int b = blockIdx.x;
    const int j = threadIdx.x;     // 0..511
    __shared__ int sl[LS], sn[LS];
    const int p = pos[b * LS + j];
    const bool pm = (p == 3) | (p == 7) | (p == 11);
    sl[j] = pm ? j : -1000;
    sn[j] = pm ? j : 1000;
    __syncthreads();
    for (int off = 1; off < LS; off <<= 1) {
        const int vl = (j >= off)      ? sl[j - off] : -1000;
        const int vn = (j + off < LS)  ? sn[j + off] : 1000;
        __syncthreads();
        if (vl > sl[j]) sl[j] = vl;
        if (vn < sn[j]) sn[j] = vn;
        __syncthreads();
    }
    out[(size_t)(b * LS + j) * OUTD] = (float)min(j - sl[j], sn[j] - j);
}

__device__ __forceinline__ void unpack4(uint2 r, float* p) {
    p[0] = __uint_as_float(r.x << 16);
    p[1] = __uint_as_float(r.x & 0xFFFF0000u);
    p[2] = __uint_as_float(r.y << 16);
    p[3] = __uint_as_float(r.y & 0xFFFF0000u);
}

// ---------- Kernel 3: main fused kernel ----------
__global__ __launch_bounds__(NTHR, 8) void main_kernel(
        const int* __restrict__ input_word,
        const int* __restrict__ input_char,
        const int* __restrict__ input_pos,
        const float* __restrict__ word_table,
        const float* __restrict__ pos_table,
        const float* __restrict__ conv_b,
        const __hip_bfloat16* __restrict__ Pg,
        float* __restrict__ out) {
    __shared__ __hip_bfloat16 Pl[NC * PROW];   // 62400 B
    __shared__ int s_addr[TPB * CL];           // 4096 B: LDS byte addr per char slot

    const int tid  = threadIdx.x;
    const int tok0 = blockIdx.x * TPB;

    // stage P into LDS as uint4 (3900 x 16B)
    {
        const uint4* src = (const uint4*)Pg;
        uint4* dst = (uint4*)Pl;
        for (int i = tid; i < PBYTES / 16; i += NTHR) dst[i] = src[i];
    }
    // stage char LDS base addresses (TPB*CL == NTHR, one per thread)
    s_addr[tid] = input_char[tok0 * CL + tid] * (PROW * 2);

    // ---- copies with no LDS dependency: overlap with P staging latency ----
    // word: out[:, 1:301]
    for (int e = tid; e < TPB * WD; e += NTHR) {
        const int t = e / WD, j = e - t * WD;
        const int w = input_word[tok0 + t];
        out[(size_t)(tok0 + t) * OUTD + 1 + j] = word_table[(size_t)w * WD + j];
    }
    // pos: out[:, 401:501]
    for (int e = tid; e < TPB * PD; e += NTHR) {
        const int t = e / PD, j = e - t * PD;
        const int p = input_pos[tok0 + t];
        out[(size_t)(tok0 + t) * OUTD + 401 + j] = pos_table[p * PD + j];
    }

    __syncthreads();

    // ---- char CNN: 25 threads per token, each owns 4 filters (one b64 quad) ----
    if (tid < TPB * 25) {
        const int tl = tid / 25;
        const int q  = tid - tl * 25;
        const char* Pb = (const char*)Pl;
        const int* ap = &s_addr[tl * CL];
        float a0[4] = {0.f, 0.f, 0.f, 0.f};
        float a1[4] = {0.f, 0.f, 0.f, 0.f};
        float m[4]  = {-1e30f, -1e30f, -1e30f, -1e30f};
        #pragma unroll 4
        for (int t = 0; t < CL; ++t) {
            const int ca = ap[t];                      // broadcast within token group
            uint2 r0 = *(const uint2*)(Pb + ca + 0 * (OPAD * 2) + q * 8);
            uint2 r1 = *(const uint2*)(Pb + ca + 1 * (OPAD * 2) + q * 8);
            uint2 r2 = *(const uint2*)(Pb + ca + 2 * (OPAD * 2) + q * 8);
            float p0[4], p1[4], p2[4];
            unpack4(r0, p0); unpack4(r1, p1); unpack4(r2, p2);
            #pragma unroll
            for (int i = 0; i < 4; ++i) {
                const float y = a0[i] + p2[i];         // y[t] complete
                m[i]  = fmaxf(m[i], y);
                a0[i] = a1[i] + p1[i];
                a1[i] = p0[i];
            }
        }
        const float4 b4 = *(const float4*)(conv_b + 4 * q);
        const float bb[4] = {b4.x, b4.y, b4.z, b4.w};
        float* outc = out + (size_t)(tok0 + tl) * OUTD + 301 + 4 * q;
        #pragma unroll
        for (int i = 0; i < 4; ++i) {
            // y[32] = a0, y[33] = a1 (tail of the sliding window)
            const float mm = fmaxf(m[i], fmaxf(a0[i], a1[i]));
            outc[i] = tanhf(mm + bb[i]);
        }
    }
}

extern "C" void kernel_launch(void* const* d_in, const int* in_sizes, int n_in,
                              void* d_out, int out_size, void* d_ws, size_t ws_size,
                              hipStream_t stream) {
    const int*   input_word = (const int*)d_in[0];
    const int*   input_char = (const int*)d_in[1];
    const int*   input_pos  = (const int*)d_in[2];
    const float* word_table = (const float*)d_in[3];
    const float* char_table = (const float*)d_in[4];
    const float* pos_table  = (const float*)d_in[5];
    const float* conv_w     = (const float*)d_in[6];
    const float* conv_b     = (const float*)d_in[7];
    float* out = (float*)d_out;

    __hip_bfloat16* P = (__hip_bfloat16*)d_ws;                 // 62400 B

    precompute_P<<<dim3(NC, KK), 128, 0, stream>>>(conv_w, char_table, P);
    dist_kernel<<<BS, LS, 0, stream>>>(input_pos, out);
    main_kernel<<<(BS * LS) / TPB, NTHR, 0, stream>>>(
        input_word, input_char, input_pos, word_table, pos_table, conv_b, P, out);
}

// Round 4
// 45.677 us; speedup vs baseline: 2.7110x; 1.2676x over previous
//
#include <hip/hip_runtime.h>
#include <hip/hip_fp16.h>

#define BS 64
#define LS 512
#define CL 32
#define WD 300
#define NC 100
#define CD 100
#define PD 100
#define NF 100
#define KK 3
#define OPAD 104                 // filters padded to 13*8
#define PROW (KK*OPAD)           // 312 halves = 624 B per char
#define PBYTES (NC*PROW*2)       // 62400 B
#define OUTD 501
#define TPB 64                   // tokens per block (divides 512: blocks never cross rows)
#define NTHR 1024
#define QPT 13                   // threads per token, 8 filters each (13*8=104)

typedef _Float16 h2 __attribute__((ext_vector_type(2)));

// ---------- Kernel 1: P[c][k][o] = sum_i conv_w[o,i,k] * char_table[c,i] (f16) ----------
__global__ void precompute_P(const float* __restrict__ conv_w,
                             const float* __restrict__ char_table,
                             _Float16* __restrict__ P) {
    const int c = blockIdx.x;      // 0..99
    const int k = blockIdx.y;      // 0..2
    const int o = threadIdx.x;     // 0..127
    __shared__ float row[CD];
    if (o < CD) row[o] = char_table[c * CD + o];
    __syncthreads();
    float acc = 0.f;
    if (o < NF) {
        const float* w = conv_w + o * (CD * KK) + k;
        #pragma unroll 4
        for (int i = 0; i < CD; ++i) acc += w[i * KK] * row[i];
    }
    if (o < OPAD) P[(c * KK + k) * OPAD + o] = (_Float16)acc;
}

__device__ __forceinline__ h2 h2of(const uint4& r, int i) {
    unsigned u = (i == 0) ? r.x : (i == 1) ? r.y : (i == 2) ? r.z : r.w;
    return __builtin_bit_cast(h2, u);
}

// ---------- Kernel 2: fused main kernel (copies + char CNN + privacy distance) ----------
__global__ __launch_bounds__(NTHR, 8) void main_kernel(
        const int* __restrict__ input_word,
        const int* __restrict__ input_char,
        const int* __restrict__ input_pos,
        const float* __restrict__ word_table,
        const float* __restrict__ pos_table,
        const float* __restrict__ conv_b,
        const _Float16* __restrict__ Pg,
        float* __restrict__ out) {
    __shared__ alignas(16) _Float16 Pl[NC * PROW];      // 62400 B
    __shared__ int s_addr[TPB * CL];                    // 8192 B
    __shared__ unsigned long long s_mask[LS / 64];      // 64 B

    const int tid  = threadIdx.x;
    const int tok0 = blockIdx.x * TPB;

    // ---- stage P into LDS (3900 x 16B) ----
    {
        const uint4* src = (const uint4*)Pg;
        uint4* dst = (uint4*)Pl;
        for (int i = tid; i < PBYTES / 16; i += NTHR) dst[i] = src[i];
    }
    // ---- stage char LDS byte addresses (TPB*CL = 2048) ----
    for (int i = tid; i < TPB * CL; i += NTHR) s_addr[i] = input_char[tok0 * CL + i] * (PROW * 2);

    // ---- privacy-mask ballot for this block's row (512 positions -> 8 words) ----
    const int row = tok0 >> 9;
    if (tid < LS) {
        const int p = input_pos[row * LS + tid];
        const bool pm = (p == 3) | (p == 7) | (p == 11);
        const unsigned long long b = __ballot(pm);
        if ((tid & 63) == 0) s_mask[tid >> 6] = b;
    }

    // ---- copies (no LDS dependency; overlap with staging latency) ----
    // word: out[:, 1:301] — float4 table loads, scalar stores (out rows 4B-aligned)
    for (int i = tid; i < TPB * (WD / 4); i += NTHR) {
        const int t = i / (WD / 4);
        const int j = i - t * (WD / 4);
        const int w = input_word[tok0 + t];
        const float4 v = ((const float4*)word_table)[(size_t)w * (WD / 4) + j];
        float* o = out + (size_t)(tok0 + t) * OUTD + 1 + 4 * j;
        o[0] = v.x; o[1] = v.y; o[2] = v.z; o[3] = v.w;
    }
    // pos: out[:, 401:501]
    for (int i = tid; i < TPB * (PD / 4); i += NTHR) {
        const int t = i / (PD / 4);
        const int j = i - t * (PD / 4);
        const int p = input_pos[tok0 + t];
        const float4 v = ((const float4*)pos_table)[p * (PD / 4) + j];
        float* o = out + (size_t)(tok0 + t) * OUTD + 401 + 4 * j;
        o[0] = v.x; o[1] = v.y; o[2] = v.z; o[3] = v.w;
    }

    __syncthreads();

    // ---- privacy distance: out[:, 0] (one thread per token, bit-scan over 8 words) ----
    if (tid < TPB) {
        const int j = (tok0 & (LS - 1)) + tid;
        const int wj = j >> 6, bj = j & 63;
        int last = -1000;
        {
            unsigned long long x = s_mask[wj] & ((2ull << bj) - 1ull);
            int w = wj;
            while (true) {
                if (x) { last = w * 64 + 63 - __clzll(x); break; }
                if (--w < 0) break;
                x = s_mask[w];
            }
        }
        int nxt = 1000;
        {
            unsigned long long x = s_mask[wj] & (~0ull << bj);
            int w = wj;
            while (true) {
                if (x) { nxt = w * 64 + (int)__ffsll((long long)x) - 1; break; }
                if (++w >= LS / 64) break;
                x = s_mask[w];
            }
        }
        out[(size_t)(tok0 + tid) * OUTD] = (float)min(j - last, nxt - j);
    }

    // ---- char CNN: 13 threads/token, 8 filters each, packed f16 sliding window ----
    if (tid < TPB * QPT) {
        const int tl = tid / QPT;
        const int q  = tid - tl * QPT;
        const char* Pb = (const char*)Pl;
        const int* ap = &s_addr[tl * CL];
        const int qo = q * 16;
        h2 a0[4], a1[4], m[4];
        #pragma unroll
        for (int i = 0; i < 4; ++i) {
            a0[i] = (h2)(_Float16)0;
            a1[i] = (h2)(_Float16)0;
            m[i]  = (h2)(_Float16)(-60000.f);
        }
        #pragma unroll 4
        for (int t = 0; t < CL; ++t) {
            const int ca = ap[t];
            const uint4 r0 = *(const uint4*)(Pb + ca + 0 * (OPAD * 2) + qo);
            const uint4 r1 = *(const uint4*)(Pb + ca + 1 * (OPAD * 2) + qo);
            const uint4 r2 = *(const uint4*)(Pb + ca + 2 * (OPAD * 2) + qo);
            #pragma unroll
            for (int i = 0; i < 4; ++i) {
                const h2 p0 = h2of(r0, i);
                const h2 p1 = h2of(r1, i);
                const h2 p2 = h2of(r2, i);
                const h2 y = a0[i] + p2;                    // y[t]
                m[i]  = __builtin_elementwise_max(m[i], y);
                a0[i] = a1[i] + p1;
                a1[i] = p0;
            }
        }
        // tail: y[32] = a0, y[33] = a1
        float mm[8];
        #pragma unroll
        for (int i = 0; i < 4; ++i) {
            const h2 v = __builtin_elementwise_max(m[i], __builtin_elementwise_max(a0[i], a1[i]));
            mm[2 * i]     = (float)v.x;
            mm[2 * i + 1] = (float)v.y;
        }
        const float4 b0 = *(const float4*)(conv_b + 8 * q);
        float* outc = out + (size_t)(tok0 + tl) * OUTD + 301 + 8 * q;
        outc[0] = tanhf(mm[0] + b0.x);
        outc[1] = tanhf(mm[1] + b0.y);
        outc[2] = tanhf(mm[2] + b0.z);
        outc[3] = tanhf(mm[3] + b0.w);
        if (q < QPT - 1) {
            const float4 b1 = *(const float4*)(conv_b + 8 * q + 4);
            outc[4] = tanhf(mm[4] + b1.x);
            outc[5] = tanhf(mm[5] + b1.y);
            outc[6] = tanhf(mm[6] + b1.z);
            outc[7] = tanhf(mm[7] + b1.w);
        }
    }
}

extern "C" void kernel_launch(void* const* d_in, const int* in_sizes, int n_in,
                              void* d_out, int out_size, void* d_ws, size_t ws_size,
                              hipStream_t stream) {
    const int*   input_word = (const int*)d_in[0];
    const int*   input_char = (const int*)d_in[1];
    const int*   input_pos  = (const int*)d_in[2];
    const float* word_table = (const float*)d_in[3];
    const float* char_table = (const float*)d_in[4];
    const float* pos_table  = (const float*)d_in[5];
    const float* conv_w     = (const float*)d_in[6];
    const float* conv_b     = (const float*)d_in[7];
    float* out = (float*)d_out;

    _Float16* P = (_Float16*)d_ws;                             // 62400 B

    precompute_P<<<dim3(NC, KK), 128, 0, stream>>>(conv_w, char_table, P);
    main_kernel<<<(BS * LS) / TPB, NTHR, 0, stream>>>(
        input_word, input_char, input_pos, word_table, pos_table, conv_b, P, out);
}